// Round 2
// baseline (609.212 us; speedup 1.0000x reference)
//
#include <hip/hip_runtime.h>
#include <hip/hip_bf16.h>

#define TB     16
#define NT     256
#define SAMPLE 512
#define HID    128
#define LATENT 32
#define HID2   256

typedef unsigned short u16;
typedef unsigned int   u32;

__device__ __forceinline__ float b2f(u16 u) {
    union { float f; u32 i; } v; v.i = ((u32)u) << 16; return v.f;
}
__device__ __forceinline__ u16 f2b(float f) {
    union { float f; u32 i; } v; v.f = f;
    u32 x = v.i;
    return (u16)((x + 0x7FFFu + ((x >> 16) & 1u)) >> 16);
}
__device__ __forceinline__ float relu(float a) { return a > 0.f ? a : 0.f; }

__global__ __launch_bounds__(NT) void ae_fused(
    const float* __restrict__ x,
    const float* __restrict__ gw,
    const float* __restrict__ gb,
    const float* __restrict__ w1,
    const float* __restrict__ b1,
    const float* __restrict__ w2,
    const float* __restrict__ b2,
    const float* __restrict__ dw1,
    const float* __restrict__ db1,
    const float* __restrict__ dw2,
    const float* __restrict__ db2,
    const float* __restrict__ dw3,
    const float* __restrict__ db3,
    const int* __restrict__ idx,
    const float* __restrict__ mask,
    float* __restrict__ out,
    int G, int K)
{
    // 48 KB LDS, phase overlays (float offsets):
    //   xs  [0,8192)     fp32 [16][512]   phases 0-1
    //   h1  [8192,12288) bf16 [16][512]   phases 1-2 (u16 packed)
    //   h2  [0,2048)     fp32 [16][128]   phases 2-3 (xs dead)
    //   zz  [2048,2560)  fp32 [16][32]    phases 3-4
    //   d1  [2560,4608)  fp32 [16][128]   phases 4-5
    //   d2  [4608,8704)  fp32 [16][256]   phases 5-6 (xs/h1 dead)
    __shared__ float smem[12288];
    float* xs = smem;
    u16*   h1 = (u16*)(smem + 8192);
    float* h2 = smem;
    float* zz = smem + 2048;
    float* d1 = smem + 2560;
    float* d2 = smem + 4608;

    const int tid = threadIdx.x;
    const int b0  = blockIdx.x * TB;

    // ---- Phase 0: stage x tile (coalesced float4) ----
    {
        const float4* xg = (const float4*)(x + (size_t)b0 * SAMPLE);
        float4* xl = (float4*)xs;
        #pragma unroll
        for (int i = 0; i < (TB * SAMPLE / 4) / NT; ++i)
            xl[tid + i * NT] = xg[tid + i * NT];
    }
    __syncthreads();

    // ---- Phase 1: h1 = relu(einsum(x[:,idx], gw*mask) + gb) ----
    for (int t = tid; t < TB * G; t += NT) {
        int r = t / G;
        int g = t - r * G;
        const float* rowx = xs + r * SAMPLE;
        float acc = 0.f;
        for (int k = 0; k < K; ++k) {
            int id = idx[g * K + k];
            acc += rowx[id] * (gw[g * K + k] * mask[g * K + k]);
        }
        h1[r * SAMPLE + g] = f2b(relu(acc + gb[g]));
    }
    __syncthreads();

    // ---- Phase 2: h2 = relu(h1 @ w1 + b1)   [TB,G]x[G,128] ----
    {
        int p = tid & 63;            // output column pair (2p, 2p+1)
        int rbase = (tid >> 6) * 4;  // 4 rows per thread
        float acc[4][2] = {};
        const float2* wu = (const float2*)w1;
        for (int g = 0; g < G; ++g) {
            float2 w = wu[g * (HID / 2) + p];
            #pragma unroll
            for (int r = 0; r < 4; ++r) {
                float v = b2f(h1[(rbase + r) * SAMPLE + g]);
                acc[r][0] += v * w.x;
                acc[r][1] += v * w.y;
            }
        }
        float bl = b1[2 * p], bh = b1[2 * p + 1];
        #pragma unroll
        for (int r = 0; r < 4; ++r) {
            h2[(rbase + r) * HID + 2 * p]     = relu(acc[r][0] + bl);
            h2[(rbase + r) * HID + 2 * p + 1] = relu(acc[r][1] + bh);
        }
    }
    __syncthreads();

    // ---- Phase 3: z = relu(h2 @ w2 + b2)   [TB,128]x[128,32] ----
    {
        int p = tid & 15;
        int r = tid >> 4;
        float a0 = 0.f, a1 = 0.f;
        const float2* wu = (const float2*)w2;
        for (int c = 0; c < HID; ++c) {
            float2 w = wu[c * (LATENT / 2) + p];
            float v = h2[r * HID + c];
            a0 += v * w.x;
            a1 += v * w.y;
        }
        zz[r * LATENT + 2 * p]     = relu(a0 + b2[2 * p]);
        zz[r * LATENT + 2 * p + 1] = relu(a1 + b2[2 * p + 1]);
    }
    __syncthreads();

    // ---- Phase 4: d1 = relu(z @ dw1 + db1)   [TB,32]x[32,128] ----
    {
        int p = tid & 63;
        int rbase = (tid >> 6) * 4;
        float acc[4][2] = {};
        const float2* wu = (const float2*)dw1;
        for (int c = 0; c < LATENT; ++c) {
            float2 w = wu[c * (HID / 2) + p];
            #pragma unroll
            for (int r = 0; r < 4; ++r) {
                float v = zz[(rbase + r) * LATENT + c];
                acc[r][0] += v * w.x;
                acc[r][1] += v * w.y;
            }
        }
        float bl = db1[2 * p], bh = db1[2 * p + 1];
        #pragma unroll
        for (int r = 0; r < 4; ++r) {
            d1[(rbase + r) * HID + 2 * p]     = relu(acc[r][0] + bl);
            d1[(rbase + r) * HID + 2 * p + 1] = relu(acc[r][1] + bh);
        }
    }
    __syncthreads();

    // ---- Phase 5: d2 = relu(d1 @ dw2 + db2)   [TB,128]x[128,256] ----
    {
        int p = tid & 127;
        int rbase = (tid >> 7) * 8;  // 8 rows per thread
        float acc[8][2] = {};
        const float2* wu = (const float2*)dw2;
        for (int c = 0; c < HID; ++c) {
            float2 w = wu[c * (HID2 / 2) + p];
            #pragma unroll
            for (int r = 0; r < 8; ++r) {
                float v = d1[(rbase + r) * HID + c];
                acc[r][0] += v * w.x;
                acc[r][1] += v * w.y;
            }
        }
        float bl = db2[2 * p], bh = db2[2 * p + 1];
        #pragma unroll
        for (int r = 0; r < 8; ++r) {
            d2[(rbase + r) * HID2 + 2 * p]     = relu(acc[r][0] + bl);
            d2[(rbase + r) * HID2 + 2 * p + 1] = relu(acc[r][1] + bh);
        }
    }
    __syncthreads();

    // ---- Phase 6: out = sigmoid(d2 @ dw3 + db3)   [TB,256]x[256,512] ----
    {
        float acc[TB][2] = {};
        const float2* wu = (const float2*)dw3;
        for (int c = 0; c < HID2; ++c) {
            float2 w = wu[c * (SAMPLE / 2) + tid];
            #pragma unroll
            for (int r = 0; r < TB; ++r) {
                float v = d2[r * HID2 + c];
                acc[r][0] += v * w.x;
                acc[r][1] += v * w.y;
            }
        }
        float bl = db3[2 * tid], bh = db3[2 * tid + 1];
        float2* outu = (float2*)out;
        #pragma unroll
        for (int r = 0; r < TB; ++r) {
            float2 o;
            o.x = 1.f / (1.f + __expf(-(acc[r][0] + bl)));
            o.y = 1.f / (1.f + __expf(-(acc[r][1] + bh)));
            outu[(size_t)(b0 + r) * (SAMPLE / 2) + tid] = o;
        }
    }
}

extern "C" void kernel_launch(void* const* d_in, const int* in_sizes, int n_in,
                              void* d_out, int out_size, void* d_ws, size_t ws_size,
                              hipStream_t stream) {
    const float* x   = (const float*)d_in[0];
    const float* gw  = (const float*)d_in[1];
    const float* gb  = (const float*)d_in[2];
    const float* w1  = (const float*)d_in[3];
    const float* b1  = (const float*)d_in[4];
    const float* w2  = (const float*)d_in[5];
    const float* b2  = (const float*)d_in[6];
    const float* dw1 = (const float*)d_in[7];
    const float* db1 = (const float*)d_in[8];
    const float* dw2 = (const float*)d_in[9];
    const float* db2 = (const float*)d_in[10];
    const float* dw3 = (const float*)d_in[11];
    const float* db3 = (const float*)d_in[12];
    const int* idx   = (const int*)d_in[13];
    const float* mask= (const float*)d_in[14];
    float* out = (float*)d_out;

    const int B = in_sizes[0] / SAMPLE;   // 8192
    const int G = in_sizes[2];            // 510
    const int K = in_sizes[1] / G;        // Kmax

    dim3 grid(B / TB);
    ae_fused<<<grid, NT, 0, stream>>>(x, gw, gb, w1, b1, w2, b2,
                                      dw1, db1, dw2, db2, dw3, db3,
                                      idx, mask, out, G, K);
}

// Round 3
// 127.462 us; speedup vs baseline: 4.7796x; 4.7796x over previous
//
#include <hip/hip_runtime.h>
#include <hip/hip_bf16.h>

#define SAMPLE 512
#define GDIM   510
#define HID    128
#define LATENT 32
#define HID2   256
#define TB     32      // batch rows per block
#define NT     512     // threads per block (8 waves)

typedef unsigned short u16;
typedef unsigned int   u32;
typedef __attribute__((ext_vector_type(8))) short s16x8;
typedef __attribute__((ext_vector_type(4))) float f32x4;

// packed-weight regions in d_ws (u16 element offsets)
// layout per matrix: [nt][kt][lane 0..63][j 0..7], chunk = 8 u16 = 16 B
#define WGP_OFF   0                         // gather W: N=512(510) K=512, 32x16 tiles
#define W1P_OFF   (WGP_OFF  + 32*16*512)    // 262144   w1:  N=128 K=512(510)
#define W2P_OFF   (W1P_OFF  + 8*16*512)     // 327680   w2:  N=32  K=128
#define DW1P_OFF  (W2P_OFF  + 2*4*512)      // 331776   dw1: N=128 K=32
#define DW2P_OFF  (DW1P_OFF + 8*1*512)      // 335872   dw2: N=256 K=128
#define DW3P_OFF  (DW2P_OFF + 16*4*512)     // 368640   dw3: N=512 K=256
#define PACK_U16  (DW3P_OFF + 32*8*512)     // 499712 u16 = 999424 B
#define NCHUNK    (PACK_U16 / 8)            // 62464 16-B chunks

__device__ __forceinline__ u16 f2b(float f) {
    union { float f; u32 i; } v; v.f = f;
    return (u16)((v.i + 0x7FFFu + ((v.i >> 16) & 1u)) >> 16);
}

// ---------------- prologue 1: pack dense weights (and zero gather-W) ----------------
__global__ __launch_bounds__(256) void pack_all(
    const float* __restrict__ w1, const float* __restrict__ w2,
    const float* __restrict__ dw1, const float* __restrict__ dw2,
    const float* __restrict__ dw3, u16* __restrict__ ws)
{
    int c = blockIdx.x * 256 + threadIdx.x;
    if (c >= NCHUNK) return;
    if (c < W1P_OFF / 8) {                 // gather-W region: zero-init
        *(s16x8*)(ws + (size_t)c * 8) = (s16x8)0;
        return;
    }
    const float* W; int Kd, Nd, KT, base;
    if      (c < W2P_OFF / 8)  { W = w1;  Kd = GDIM; Nd = HID;    KT = 16; base = W1P_OFF / 8; }
    else if (c < DW1P_OFF / 8) { W = w2;  Kd = HID;  Nd = LATENT; KT = 4;  base = W2P_OFF / 8; }
    else if (c < DW2P_OFF / 8) { W = dw1; Kd = LATENT; Nd = HID;  KT = 1;  base = DW1P_OFF / 8; }
    else if (c < DW3P_OFF / 8) { W = dw2; Kd = HID;  Nd = HID2;   KT = 4;  base = DW2P_OFF / 8; }
    else                       { W = dw3; Kd = HID2; Nd = SAMPLE; KT = 8;  base = DW3P_OFF / 8; }
    int c2   = c - base;
    int lane = c2 & 63;
    int kt   = (c2 >> 6) % KT;
    int nt   = (c2 >> 6) / KT;
    int n    = nt * 16 + (lane & 15);
    int k0   = kt * 32 + (lane >> 4) * 8;
    u16 tmp[8];
    #pragma unroll
    for (int j = 0; j < 8; ++j) {
        int k = k0 + j;
        float v = (k < Kd && n < Nd) ? W[(size_t)k * Nd + n] : 0.f;
        tmp[j] = f2b(v);
    }
    *(s16x8*)(ws + (size_t)c * 8) = *(s16x8*)tmp;
}

// ---------------- prologue 2: scatter gather weights into dense packed W ----------------
__global__ __launch_bounds__(256) void scatter_gw(
    const float* __restrict__ gw, const float* __restrict__ mask,
    const int* __restrict__ idx, u16* __restrict__ ws, int total, int K)
{
    int t = blockIdx.x * 256 + threadIdx.x;
    if (t >= total) return;
    float m = mask[t];
    if (m == 0.f) return;                  // skip pads (pad idx==0 would collide)
    int g = t / K;
    int s = idx[t];                        // row (k-dim) in dense W
    float v = gw[t] * m;
    int nt = g >> 4, kt = s >> 5;
    int lane = ((s >> 3) & 3) * 16 + (g & 15);
    int j = s & 7;
    ws[WGP_OFF + (size_t)(((nt * 16 + kt) * 64 + lane) * 8 + j)] = f2b(v);
}

// ---------------- generic MFMA phase ----------------
// M=32 (2 m-tiles), N = NTN*16, K = KT*32. 8 waves; wave w owns m-tile (w&1),
// n-tiles (w>>1)+4i. A from LDS bf16 (stride sin), B from packed global,
// out = relu(acc+bias) -> LDS bf16 (stride sout).
template<int KT, int NTN, int TPW>
__device__ __forceinline__ void mfma_phase(
    int wave, int lane,
    const u16* inl, int sin,
    const u16* __restrict__ pW,
    const float* bias,
    u16* outl, int sout)
{
    if (2 * NTN < 8 && wave >= 2 * NTN) return;
    const int mt = wave & 1;
    const u16* arow = inl + (mt * 16 + (lane & 15)) * sin + (lane >> 4) * 8;
    f32x4 acc[TPW];
    #pragma unroll
    for (int i = 0; i < TPW; ++i) acc[i] = (f32x4){0.f, 0.f, 0.f, 0.f};
    #pragma unroll
    for (int kt = 0; kt < KT; ++kt) {
        s16x8 a = *(const s16x8*)(arow + kt * 32);
        #pragma unroll
        for (int i = 0; i < TPW; ++i) {
            int nt = (wave + 8 * i) >> 1;
            s16x8 b = *(const s16x8*)(pW + (size_t)((nt * KT + kt) * 64 + lane) * 8);
            acc[i] = __builtin_amdgcn_mfma_f32_16x16x32_bf16(a, b, acc[i], 0, 0, 0);
        }
    }
    #pragma unroll
    for (int i = 0; i < TPW; ++i) {
        int nt = (wave + 8 * i) >> 1;
        int col = nt * 16 + (lane & 15);
        float bs = bias[col];
        #pragma unroll
        for (int r = 0; r < 4; ++r) {
            int row = mt * 16 + (lane >> 4) * 4 + r;
            float v = acc[i][r] + bs;
            outl[row * sout + col] = f2b(v > 0.f ? v : 0.f);
        }
    }
}

// ---------------- fused main kernel ----------------
__global__ __launch_bounds__(NT) void ae_mfma(
    const float* __restrict__ x,
    const float* __restrict__ gb,  const float* __restrict__ b1,
    const float* __restrict__ b2,  const float* __restrict__ db1,
    const float* __restrict__ db2, const float* __restrict__ db3,
    const u16*   __restrict__ ws,
    float* __restrict__ out)
{
    // padded strides (u16 elems): keep rows 16B-aligned, stride%32dw==4 for bank spread
    __shared__ __align__(16) u16 xs[TB * 520];
    __shared__ __align__(16) u16 h1[TB * 520];
    __shared__ __align__(16) u16 h2[TB * 136];
    __shared__ __align__(16) u16 zz[TB * 40];
    __shared__ __align__(16) u16 d1[TB * 136];
    __shared__ __align__(16) u16 d2[TB * 264];
    __shared__ float biases[1568];   // gb512 | b1 128 | b2 32 | db1 128 | db2 256 | db3 512

    const int tid  = threadIdx.x;
    const int wave = tid >> 6;
    const int lane = tid & 63;
    const int b0   = blockIdx.x * TB;

    // stage biases (gb zero-padded to 512)
    biases[tid]        = (tid < GDIM) ? gb[tid] : 0.f;
    biases[1056 + tid] = db3[tid];
    if (tid < 128) biases[512 + tid] = b1[tid];
    if (tid < 32)  biases[640 + tid] = b2[tid];
    if (tid < 128) biases[672 + tid] = db1[tid];
    if (tid < 256) biases[800 + tid] = db2[tid];

    // stage x tile -> bf16 LDS
    {
        const float4* xg = (const float4*)(x + (size_t)b0 * SAMPLE);
        #pragma unroll
        for (int it = 0; it < (TB * SAMPLE / 4) / NT; ++it) {
            int v = it * NT + tid;             // float4 index
            float4 f = xg[v];
            int row = v >> 7;                  // 128 float4 per row
            int cp  = (v & 127) * 4;
            u16* p = xs + row * 520 + cp;
            u16 t4[4] = { f2b(f.x), f2b(f.y), f2b(f.z), f2b(f.w) };
            *(unsigned long long*)p = *(unsigned long long*)t4;
        }
    }
    __syncthreads();

    // A: h1 = relu(x @ Wg + gb)        [32,512] x [512,512]
    mfma_phase<16, 32, 8>(wave, lane, xs, 520, ws + WGP_OFF,  biases,        h1, 520);
    __syncthreads();
    // B: h2 = relu(h1 @ w1 + b1)       [32,512] x [512,128]
    mfma_phase<16, 8, 2>(wave, lane, h1, 520, ws + W1P_OFF,  biases + 512,  h2, 136);
    __syncthreads();
    // C: z = relu(h2 @ w2 + b2)        [32,128] x [128,32]
    mfma_phase<4, 2, 1>(wave, lane, h2, 136, ws + W2P_OFF,  biases + 640,  zz, 40);
    __syncthreads();
    // D: d1 = relu(z @ dw1 + db1)      [32,32] x [32,128]
    mfma_phase<1, 8, 2>(wave, lane, zz, 40,  ws + DW1P_OFF, biases + 672,  d1, 136);
    __syncthreads();
    // E: d2 = relu(d1 @ dw2 + db2)     [32,128] x [128,256]
    mfma_phase<4, 16, 4>(wave, lane, d1, 136, ws + DW2P_OFF, biases + 800,  d2, 264);
    __syncthreads();

    // F: out = sigmoid(d2 @ dw3 + db3) [32,256] x [256,512] -> global fp32
    {
        const int mt = wave & 1;
        const u16* arow = d2 + (mt * 16 + (lane & 15)) * 264 + (lane >> 4) * 8;
        const u16* pW = ws + DW3P_OFF;
        f32x4 acc[8];
        #pragma unroll
        for (int i = 0; i < 8; ++i) acc[i] = (f32x4){0.f, 0.f, 0.f, 0.f};
        #pragma unroll
        for (int kt = 0; kt < 8; ++kt) {
            s16x8 a = *(const s16x8*)(arow + kt * 32);
            #pragma unroll
            for (int i = 0; i < 8; ++i) {
                int nt = (wave + 8 * i) >> 1;
                s16x8 b = *(const s16x8*)(pW + (size_t)((nt * 8 + kt) * 64 + lane) * 8);
                acc[i] = __builtin_amdgcn_mfma_f32_16x16x32_bf16(a, b, acc[i], 0, 0, 0);
            }
        }
        #pragma unroll
        for (int i = 0; i < 8; ++i) {
            int nt = (wave + 8 * i) >> 1;
            int col = nt * 16 + (lane & 15);
            float bs = biases[1056 + col];
            #pragma unroll
            for (int r = 0; r < 4; ++r) {
                int row = mt * 16 + (lane >> 4) * 4 + r;
                float v = acc[i][r] + bs;
                out[(size_t)(b0 + row) * SAMPLE + col] = 1.f / (1.f + __expf(-v));
            }
        }
    }
}

extern "C" void kernel_launch(void* const* d_in, const int* in_sizes, int n_in,
                              void* d_out, int out_size, void* d_ws, size_t ws_size,
                              hipStream_t stream) {
    const float* x   = (const float*)d_in[0];
    const float* gw  = (const float*)d_in[1];
    const float* gb  = (const float*)d_in[2];
    const float* w1  = (const float*)d_in[3];
    const float* b1  = (const float*)d_in[4];
    const float* w2  = (const float*)d_in[5];
    const float* b2  = (const float*)d_in[6];
    const float* dw1 = (const float*)d_in[7];
    const float* db1 = (const float*)d_in[8];
    const float* dw2 = (const float*)d_in[9];
    const float* db2 = (const float*)d_in[10];
    const float* dw3 = (const float*)d_in[11];
    const float* db3 = (const float*)d_in[12];
    const int* idx   = (const int*)d_in[13];
    const float* mask= (const float*)d_in[14];
    float* out = (float*)d_out;
    u16* ws = (u16*)d_ws;

    const int B  = in_sizes[0] / SAMPLE;     // 8192
    const int G  = in_sizes[2];              // 510
    const int K  = in_sizes[1] / G;          // 28
    const int GK = in_sizes[1];

    pack_all<<<(NCHUNK + 255) / 256, 256, 0, stream>>>(w1, w2, dw1, dw2, dw3, ws);
    scatter_gw<<<(GK + 255) / 256, 256, 0, stream>>>(gw, mask, idx, ws, GK, K);
    ae_mfma<<<B / TB, NT, 0, stream>>>(x, gb, b1, b2, db1, db2, db3, ws, out);
}

// Round 4
// 123.160 us; speedup vs baseline: 4.9465x; 1.0349x over previous
//
#include <hip/hip_runtime.h>
#include <hip/hip_bf16.h>

#define SAMPLE 512
#define GDIM   510
#define HID    128
#define LATENT 32
#define HID2   256
#define TB     16      // batch rows per block (one 16-row m-tile)
#define NT     512     // 8 waves

typedef unsigned short u16;
typedef unsigned int   u32;
typedef __attribute__((ext_vector_type(8))) short s16x8;
typedef __attribute__((ext_vector_type(4))) float f32x4;

// packed-weight regions in d_ws (u16 element offsets)
// layout per matrix: [nt][kt][lane 0..63][j 0..7], chunk = 8 u16 = 16 B
#define WGP_OFF   0                         // gather W: N=512(510) K=512
#define W1P_OFF   (WGP_OFF  + 32*16*512)    // w1:  N=128 K=512(510)
#define W2P_OFF   (W1P_OFF  + 8*16*512)     // w2:  N=32  K=128
#define DW1P_OFF  (W2P_OFF  + 2*4*512)      // dw1: N=128 K=32
#define DW2P_OFF  (DW1P_OFF + 8*1*512)      // dw2: N=256 K=128
#define DW3P_OFF  (DW2P_OFF + 16*4*512)     // dw3: N=512 K=256
#define PACK_U16  (DW3P_OFF + 32*8*512)
#define NCHUNK    (PACK_U16 / 8)

__device__ __forceinline__ u16 f2b(float f) {
    union { float f; u32 i; } v; v.f = f;
    return (u16)((v.i + 0x7FFFu + ((v.i >> 16) & 1u)) >> 16);
}

// ---------------- prologue 1: pack dense weights (and zero gather-W) ----------------
__global__ __launch_bounds__(256) void pack_all(
    const float* __restrict__ w1, const float* __restrict__ w2,
    const float* __restrict__ dw1, const float* __restrict__ dw2,
    const float* __restrict__ dw3, u16* __restrict__ ws)
{
    int c = blockIdx.x * 256 + threadIdx.x;
    if (c >= NCHUNK) return;
    if (c < W1P_OFF / 8) {                 // gather-W region: zero-init
        *(s16x8*)(ws + (size_t)c * 8) = (s16x8)0;
        return;
    }
    const float* W; int Kd, Nd, KT, base;
    if      (c < W2P_OFF / 8)  { W = w1;  Kd = GDIM;   Nd = HID;    KT = 16; base = W1P_OFF / 8; }
    else if (c < DW1P_OFF / 8) { W = w2;  Kd = HID;    Nd = LATENT; KT = 4;  base = W2P_OFF / 8; }
    else if (c < DW2P_OFF / 8) { W = dw1; Kd = LATENT; Nd = HID;    KT = 1;  base = DW1P_OFF / 8; }
    else if (c < DW3P_OFF / 8) { W = dw2; Kd = HID;    Nd = HID2;   KT = 4;  base = DW2P_OFF / 8; }
    else                       { W = dw3; Kd = HID2;   Nd = SAMPLE; KT = 8;  base = DW3P_OFF / 8; }
    int c2   = c - base;
    int lane = c2 & 63;
    int kt   = (c2 >> 6) % KT;
    int nt   = (c2 >> 6) / KT;
    int n    = nt * 16 + (lane & 15);
    int k0   = kt * 32 + (lane >> 4) * 8;
    u16 tmp[8];
    #pragma unroll
    for (int j = 0; j < 8; ++j) {
        int k = k0 + j;
        float v = (k < Kd && n < Nd) ? W[(size_t)k * Nd + n] : 0.f;
        tmp[j] = f2b(v);
    }
    *(s16x8*)(ws + (size_t)c * 8) = *(s16x8*)tmp;
}

// ---------------- prologue 2: scatter gather weights into dense packed W ----------------
__global__ __launch_bounds__(256) void scatter_gw(
    const float* __restrict__ gw, const float* __restrict__ mask,
    const int* __restrict__ idx, u16* __restrict__ ws, int total, int K)
{
    int t = blockIdx.x * 256 + threadIdx.x;
    if (t >= total) return;
    float m = mask[t];
    if (m == 0.f) return;                  // skip pads
    int g = t / K;
    int s = idx[t];                        // k-dim row in dense W
    float v = gw[t] * m;
    int nt = g >> 4, kt = s >> 5;
    int lane = ((s >> 3) & 3) * 16 + (g & 15);
    int j = s & 7;
    ws[WGP_OFF + (size_t)(((nt * 16 + kt) * 64 + lane) * 8 + j)] = f2b(v);
}

// ---------------- generic MFMA phase (M=16, one m-tile) ----------------
// N = NTN*16, K = KT*32. 8 waves; wave w owns n-tiles w + 8*i (i<TPW).
// For NTN<8 only waves < NTN are active (TPW=1).
template<int KT, int NTN, int TPW>
__device__ __forceinline__ void mfma_phase(
    int wave, int lane,
    const u16* inl, int sin,
    const u16* __restrict__ pW,
    const float* bias,
    u16* outl, int sout)
{
    if (NTN < 8 && wave >= NTN) return;
    const u16* arow = inl + (lane & 15) * sin + (lane >> 4) * 8;
    f32x4 acc[TPW];
    #pragma unroll
    for (int i = 0; i < TPW; ++i) acc[i] = (f32x4){0.f, 0.f, 0.f, 0.f};
    #pragma unroll
    for (int kt = 0; kt < KT; ++kt) {
        s16x8 a = *(const s16x8*)(arow + kt * 32);
        #pragma unroll
        for (int i = 0; i < TPW; ++i) {
            int nt = wave + 8 * i;
            s16x8 b = *(const s16x8*)(pW + (size_t)((nt * KT + kt) * 64 + lane) * 8);
            acc[i] = __builtin_amdgcn_mfma_f32_16x16x32_bf16(a, b, acc[i], 0, 0, 0);
        }
    }
    #pragma unroll
    for (int i = 0; i < TPW; ++i) {
        int nt = wave + 8 * i;
        int col = nt * 16 + (lane & 15);
        float bs = bias[col];
        #pragma unroll
        for (int r = 0; r < 4; ++r) {
            int row = (lane >> 4) * 4 + r;
            float v = acc[i][r] + bs;
            outl[row * sout + col] = f2b(v > 0.f ? v : 0.f);
        }
    }
}

// ---------------- fused main kernel ----------------
__global__ __launch_bounds__(NT) void ae_mfma(
    const float* __restrict__ x,
    const float* __restrict__ gb,  const float* __restrict__ b1,
    const float* __restrict__ b2,  const float* __restrict__ db1,
    const float* __restrict__ db2, const float* __restrict__ db3,
    const u16*   __restrict__ ws,
    float* __restrict__ out)
{
    __shared__ __align__(16) u16 xs[TB * 520];
    __shared__ __align__(16) u16 h1[TB * 520];
    __shared__ __align__(16) u16 h2[TB * 136];
    __shared__ __align__(16) u16 zz[TB * 40];
    __shared__ __align__(16) u16 d1[TB * 136];
    __shared__ __align__(16) u16 d2[TB * 264];
    __shared__ float biases[1568];   // gb512 | b1 128 | b2 32 | db1 128 | db2 256 | db3 512

    const int tid  = threadIdx.x;
    const int wave = tid >> 6;
    const int lane = tid & 63;
    const int b0   = blockIdx.x * TB;

    // stage biases (gb zero-padded to 512)
    biases[tid]        = (tid < GDIM) ? gb[tid] : 0.f;
    biases[1056 + tid] = db3[tid];
    if (tid < 128) biases[512 + tid] = b1[tid];
    if (tid < 32)  biases[640 + tid] = b2[tid];
    if (tid < 128) biases[672 + tid] = db1[tid];
    if (tid < 256) biases[800 + tid] = db2[tid];

    // stage x tile -> bf16 LDS
    {
        const float4* xg = (const float4*)(x + (size_t)b0 * SAMPLE);
        #pragma unroll
        for (int it = 0; it < (TB * SAMPLE / 4) / NT; ++it) {
            int v = it * NT + tid;             // float4 index
            float4 f = xg[v];
            int row = v >> 7;                  // 128 float4 per row
            int cp  = (v & 127) * 4;
            u16* p = xs + row * 520 + cp;
            u16 t4[4] = { f2b(f.x), f2b(f.y), f2b(f.z), f2b(f.w) };
            *(unsigned long long*)p = *(unsigned long long*)t4;
        }
    }
    __syncthreads();

    // A: h1 = relu(x @ Wg + gb)        [16,512] x [512,512]
    mfma_phase<16, 32, 4>(wave, lane, xs, 520, ws + WGP_OFF,  biases,       h1, 520);
    __syncthreads();
    // B: h2 = relu(h1 @ w1 + b1)       [16,512] x [512,128]
    mfma_phase<16, 8, 1>(wave, lane, h1, 520, ws + W1P_OFF,  biases + 512, h2, 136);
    __syncthreads();
    // C: z = relu(h2 @ w2 + b2)        [16,128] x [128,32]
    mfma_phase<4, 2, 1>(wave, lane, h2, 136, ws + W2P_OFF,  biases + 640, zz, 40);
    __syncthreads();
    // D: d1 = relu(z @ dw1 + db1)      [16,32] x [32,128]
    mfma_phase<1, 8, 1>(wave, lane, zz, 40,  ws + DW1P_OFF, biases + 672, d1, 136);
    __syncthreads();
    // E: d2 = relu(d1 @ dw2 + db2)     [16,128] x [128,256]
    mfma_phase<4, 16, 2>(wave, lane, d1, 136, ws + DW2P_OFF, biases + 800, d2, 264);
    __syncthreads();

    // F: out = sigmoid(d2 @ dw3 + db3) [16,256] x [256,512] -> global fp32
    {
        const u16* arow = d2 + (lane & 15) * 264 + (lane >> 4) * 8;
        const u16* pW = ws + DW3P_OFF;
        f32x4 acc[4];
        #pragma unroll
        for (int i = 0; i < 4; ++i) acc[i] = (f32x4){0.f, 0.f, 0.f, 0.f};
        #pragma unroll
        for (int kt = 0; kt < 8; ++kt) {
            s16x8 a = *(const s16x8*)(arow + kt * 32);
            #pragma unroll
            for (int i = 0; i < 4; ++i) {
                int nt = wave + 8 * i;
                s16x8 b = *(const s16x8*)(pW + (size_t)((nt * 8 + kt) * 64 + lane) * 8);
                acc[i] = __builtin_amdgcn_mfma_f32_16x16x32_bf16(a, b, acc[i], 0, 0, 0);
            }
        }
        #pragma unroll
        for (int i = 0; i < 4; ++i) {
            int nt = wave + 8 * i;
            int col = nt * 16 + (lane & 15);
            float bs = biases[1056 + col];
            #pragma unroll
            for (int r = 0; r < 4; ++r) {
                int row = (lane >> 4) * 4 + r;
                float v = acc[i][r] + bs;
                out[(size_t)(b0 + row) * SAMPLE + col] = 1.f / (1.f + __expf(-v));
            }
        }
    }
}

extern "C" void kernel_launch(void* const* d_in, const int* in_sizes, int n_in,
                              void* d_out, int out_size, void* d_ws, size_t ws_size,
                              hipStream_t stream) {
    const float* x   = (const float*)d_in[0];
    const float* gw  = (const float*)d_in[1];
    const float* gb  = (const float*)d_in[2];
    const float* w1  = (const float*)d_in[3];
    const float* b1  = (const float*)d_in[4];
    const float* w2  = (const float*)d_in[5];
    const float* b2  = (const float*)d_in[6];
    const float* dw1 = (const float*)d_in[7];
    const float* db1 = (const float*)d_in[8];
    const float* dw2 = (const float*)d_in[9];
    const float* db2 = (const float*)d_in[10];
    const float* dw3 = (const float*)d_in[11];
    const float* db3 = (const float*)d_in[12];
    const int* idx   = (const int*)d_in[13];
    const float* mask= (const float*)d_in[14];
    float* out = (float*)d_out;
    u16* ws = (u16*)d_ws;

    const int B  = in_sizes[0] / SAMPLE;     // 8192
    const int G  = in_sizes[2];              // 510
    const int K  = in_sizes[1] / G;          // 28
    const int GK = in_sizes[1];

    pack_all<<<(NCHUNK + 255) / 256, 256, 0, stream>>>(w1, w2, dw1, dw2, dw3, ws);
    scatter_gw<<<(GK + 255) / 256, 256, 0, stream>>>(gw, mask, idx, ws, GK, K);
    ae_mfma<<<B / TB, NT, 0, stream>>>(x, gb, b1, b2, db1, db2, db3, ws, out);
}

// Round 6
// 119.616 us; speedup vs baseline: 5.0931x; 1.0296x over previous
//
#include <hip/hip_runtime.h>
#include <hip/hip_bf16.h>

#define SAMPLE 512
#define GDIM   510
#define HID    128
#define LATENT 32
#define HID2   256
#define TB     32      // batch rows per block = two 16-row m-tiles
#define NT     512     // 8 waves

typedef unsigned short u16;
typedef unsigned int   u32;
typedef __attribute__((ext_vector_type(8))) short s16x8;
typedef __attribute__((ext_vector_type(4))) float f32x4;

// packed-weight regions in d_ws (u16 element offsets)
// layout per matrix: [nt][kt][lane 0..63][j 0..7], chunk = 8 u16 = 16 B
#define WGP_OFF   0                         // gather W: N=512(510) K=512
#define W1P_OFF   (WGP_OFF  + 32*16*512)    // w1:  N=128 K=512(510)
#define W2P_OFF   (W1P_OFF  + 8*16*512)     // w2:  N=32  K=128
#define DW1P_OFF  (W2P_OFF  + 2*4*512)      // dw1: N=128 K=32
#define DW2P_OFF  (DW1P_OFF + 8*1*512)      // dw2: N=256 K=128
#define DW3P_OFF  (DW2P_OFF + 16*4*512)     // dw3: N=512 K=256
#define PACK_U16  (DW3P_OFF + 32*8*512)
#define NCHUNK    (PACK_U16 / 8)

__device__ __forceinline__ u16 f2b(float f) {
    union { float f; u32 i; } v; v.f = f;
    return (u16)((v.i + 0x7FFFu + ((v.i >> 16) & 1u)) >> 16);
}

// ---------------- prologue 1: pack dense weights (and zero gather-W) ----------------
__global__ __launch_bounds__(256) void pack_all(
    const float* __restrict__ w1, const float* __restrict__ w2,
    const float* __restrict__ dw1, const float* __restrict__ dw2,
    const float* __restrict__ dw3, u16* __restrict__ ws)
{
    int c = blockIdx.x * 256 + threadIdx.x;
    if (c >= NCHUNK) return;
    if (c < W1P_OFF / 8) {                 // gather-W region: zero-init
        *(s16x8*)(ws + (size_t)c * 8) = (s16x8)0;
        return;
    }
    const float* W; int Kd, Nd, KT, base;
    if      (c < W2P_OFF / 8)  { W = w1;  Kd = GDIM;   Nd = HID;    KT = 16; base = W1P_OFF / 8; }
    else if (c < DW1P_OFF / 8) { W = w2;  Kd = HID;    Nd = LATENT; KT = 4;  base = W2P_OFF / 8; }
    else if (c < DW2P_OFF / 8) { W = dw1; Kd = LATENT; Nd = HID;    KT = 1;  base = DW1P_OFF / 8; }
    else if (c < DW3P_OFF / 8) { W = dw2; Kd = HID;    Nd = HID2;   KT = 4;  base = DW2P_OFF / 8; }
    else                       { W = dw3; Kd = HID2;   Nd = SAMPLE; KT = 8;  base = DW3P_OFF / 8; }
    int c2   = c - base;
    int lane = c2 & 63;
    int kt   = (c2 >> 6) % KT;
    int nt   = (c2 >> 6) / KT;
    int n    = nt * 16 + (lane & 15);
    int k0   = kt * 32 + (lane >> 4) * 8;
    u16 tmp[8];
    #pragma unroll
    for (int j = 0; j < 8; ++j) {
        int k = k0 + j;
        float v = (k < Kd && n < Nd) ? W[(size_t)k * Nd + n] : 0.f;
        tmp[j] = f2b(v);
    }
    *(s16x8*)(ws + (size_t)c * 8) = *(s16x8*)tmp;
}

// ---------------- prologue 2: scatter gather weights into dense packed W ----------------
__global__ __launch_bounds__(256) void scatter_gw(
    const float* __restrict__ gw, const float* __restrict__ mask,
    const int* __restrict__ idx, u16* __restrict__ ws, int total, int K)
{
    int t = blockIdx.x * 256 + threadIdx.x;
    if (t >= total) return;
    float m = mask[t];
    if (m == 0.f) return;                  // skip pads
    int g = t / K;
    int s = idx[t];                        // k-dim row in dense W
    float v = gw[t] * m;
    int nt = g >> 4, kt = s >> 5;
    int lane = ((s >> 3) & 3) * 16 + (g & 15);
    int j = s & 7;
    ws[WGP_OFF + (size_t)(((nt * 16 + kt) * 64 + lane) * 8 + j)] = f2b(v);
}

// ---------------- generic MFMA phase: M=32 (2 m-tiles per wave, b reused) ----------------
// N = NTN*16, K = KT*32. 8 waves; wave w owns n-tiles w + 8*i (i<TPW).
template<int KT, int NTN, int TPW>
__device__ __forceinline__ void mfma_phase(
    int wave, int lane,
    const u16* inl, int sin,
    const u16* __restrict__ pW,
    const float* bias,
    u16* outl, int sout)
{
    if (NTN < 8 && wave >= NTN) return;
    const u16* arow0 = inl + (lane & 15) * sin + (lane >> 4) * 8;
    const u16* arow1 = arow0 + 16 * sin;
    f32x4 acc[TPW][2];
    #pragma unroll
    for (int i = 0; i < TPW; ++i) {
        acc[i][0] = (f32x4){0.f, 0.f, 0.f, 0.f};
        acc[i][1] = (f32x4){0.f, 0.f, 0.f, 0.f};
    }
    #pragma unroll
    for (int kt = 0; kt < KT; ++kt) {
        s16x8 a0 = *(const s16x8*)(arow0 + kt * 32);
        s16x8 a1 = *(const s16x8*)(arow1 + kt * 32);
        #pragma unroll
        for (int i = 0; i < TPW; ++i) {
            int nt = wave + 8 * i;
            s16x8 b = *(const s16x8*)(pW + (size_t)((nt * KT + kt) * 64 + lane) * 8);
            acc[i][0] = __builtin_amdgcn_mfma_f32_16x16x32_bf16(a0, b, acc[i][0], 0, 0, 0);
            acc[i][1] = __builtin_amdgcn_mfma_f32_16x16x32_bf16(a1, b, acc[i][1], 0, 0, 0);
        }
    }
    #pragma unroll
    for (int i = 0; i < TPW; ++i) {
        int nt = wave + 8 * i;
        int col = nt * 16 + (lane & 15);
        float bs = bias[col];
        #pragma unroll
        for (int mt = 0; mt < 2; ++mt) {
            #pragma unroll
            for (int r = 0; r < 4; ++r) {
                int row = mt * 16 + (lane >> 4) * 4 + r;
                float v = acc[i][mt][r] + bs;
                outl[row * sout + col] = f2b(v > 0.f ? v : 0.f);
            }
        }
    }
}

// ---------------- fused main kernel ----------------
// LDS union overlay (u16 offsets):
//   region0 [0,18432): xs [32][520] (phases 0-A) / h2@0 [32][136], zz@4352 [32][40],
//                      d1@5632 [32][136], d2@9984 [32][264] (phases B-F)
//   region1 [18432,35072): h1 [32][520] (phases A-B)
#define XS_OFF 0
#define H2_OFF 0
#define ZZ_OFF 4352
#define D1_OFF 5632
#define D2_OFF 9984
#define H1_OFF 18432
#define SMEM_U16 35072

__global__ __launch_bounds__(NT, 4) void ae_mfma(
    const float* __restrict__ x,
    const float* __restrict__ gb,  const float* __restrict__ b1,
    const float* __restrict__ b2,  const float* __restrict__ db1,
    const float* __restrict__ db2, const float* __restrict__ db3,
    const u16*   __restrict__ ws,
    float* __restrict__ out)
{
    __shared__ __align__(16) u16 smem[SMEM_U16];
    __shared__ float biases[1568];   // gb512 | b1 128 | b2 32 | db1 128 | db2 256 | db3 512
    u16* xs = smem + XS_OFF;
    u16* h1 = smem + H1_OFF;
    u16* h2 = smem + H2_OFF;
    u16* zz = smem + ZZ_OFF;
    u16* d1 = smem + D1_OFF;
    u16* d2 = smem + D2_OFF;

    const int tid  = threadIdx.x;
    const int wave = tid >> 6;
    const int lane = tid & 63;
    const int b0   = blockIdx.x * TB;

    // stage biases (gb zero-padded to 512)
    biases[tid]        = (tid < GDIM) ? gb[tid] : 0.f;
    biases[1056 + tid] = db3[tid];
    if (tid < 128) biases[512 + tid] = b1[tid];
    if (tid < 32)  biases[640 + tid] = b2[tid];
    if (tid < 128) biases[672 + tid] = db1[tid];
    if (tid < 256) biases[800 + tid] = db2[tid];

    // stage x tile -> bf16 LDS
    {
        const float4* xg = (const float4*)(x + (size_t)b0 * SAMPLE);
        #pragma unroll
        for (int it = 0; it < (TB * SAMPLE / 4) / NT; ++it) {
            int v = it * NT + tid;             // float4 index
            float4 f = xg[v];
            int row = v >> 7;                  // 128 float4 per row
            int cp  = (v & 127) * 4;
            u16* p = xs + row * 520 + cp;
            u16 t4[4] = { f2b(f.x), f2b(f.y), f2b(f.z), f2b(f.w) };
            *(unsigned long long*)p = *(unsigned long long*)t4;
        }
    }
    __syncthreads();

    // A: h1 = relu(x @ Wg + gb)        [32,512] x [512,512]
    mfma_phase<16, 32, 4>(wave, lane, xs, 520, ws + WGP_OFF,  biases,       h1, 520);
    __syncthreads();
    // B: h2 = relu(h1 @ w1 + b1)       [32,512] x [512,128]   (h2 overlays dead xs)
    mfma_phase<16, 8, 1>(wave, lane, h1, 520, ws + W1P_OFF,  biases + 512, h2, 136);
    __syncthreads();
    // C: z = relu(h2 @ w2 + b2)        [32,128] x [128,32]
    mfma_phase<4, 2, 1>(wave, lane, h2, 136, ws + W2P_OFF,  biases + 640, zz, 40);
    __syncthreads();
    // D: d1 = relu(z @ dw1 + db1)      [32,32] x [32,128]
    mfma_phase<1, 8, 1>(wave, lane, zz, 40,  ws + DW1P_OFF, biases + 672, d1, 136);
    __syncthreads();
    // E: d2 = relu(d1 @ dw2 + db2)     [32,128] x [128,256]
    mfma_phase<4, 16, 2>(wave, lane, d1, 136, ws + DW2P_OFF, biases + 800, d2, 264);
    __syncthreads();

    // F: out = sigmoid(d2 @ dw3 + db3) [32,256] x [256,512] -> global fp32
    {
        const u16* arow0 = d2 + (lane & 15) * 264 + (lane >> 4) * 8;
        const u16* arow1 = arow0 + 16 * 264;
        const u16* pW = ws + DW3P_OFF;
        f32x4 acc[4][2];
        #pragma unroll
        for (int i = 0; i < 4; ++i) {
            acc[i][0] = (f32x4){0.f, 0.f, 0.f, 0.f};
            acc[i][1] = (f32x4){0.f, 0.f, 0.f, 0.f};
        }
        #pragma unroll
        for (int kt = 0; kt < 8; ++kt) {
            s16x8 a0 = *(const s16x8*)(arow0 + kt * 32);
            s16x8 a1 = *(const s16x8*)(arow1 + kt * 32);
            #pragma unroll
            for (int i = 0; i < 4; ++i) {
                int nt = wave + 8 * i;
                s16x8 b = *(const s16x8*)(pW + (size_t)((nt * 8 + kt) * 64 + lane) * 8);
                acc[i][0] = __builtin_amdgcn_mfma_f32_16x16x32_bf16(a0, b, acc[i][0], 0, 0, 0);
                acc[i][1] = __builtin_amdgcn_mfma_f32_16x16x32_bf16(a1, b, acc[i][1], 0, 0, 0);
            }
        }
        #pragma unroll
        for (int i = 0; i < 4; ++i) {
            int nt = wave + 8 * i;
            int col = nt * 16 + (lane & 15);
            float bs = biases[1056 + col];
            #pragma unroll
            for (int mt = 0; mt < 2; ++mt) {
                #pragma unroll
                for (int r = 0; r < 4; ++r) {
                    int row = mt * 16 + (lane >> 4) * 4 + r;
                    float v = acc[i][mt][r] + bs;
                    out[(size_t)(b0 + row) * SAMPLE + col] = 1.f / (1.f + __expf(-v));
                }
            }
        }
    }
}

extern "C" void kernel_launch(void* const* d_in, const int* in_sizes, int n_in,
                              void* d_out, int out_size, void* d_ws, size_t ws_size,
                              hipStream_t stream) {
    const float* x   = (const float*)d_in[0];
    const float* gw  = (const float*)d_in[1];
    const float* gb  = (const float*)d_in[2];
    const float* w1  = (const float*)d_in[3];
    const float* b1  = (const float*)d_in[4];
    const float* w2  = (const float*)d_in[5];
    const float* b2  = (const float*)d_in[6];
    const float* dw1 = (const float*)d_in[7];
    const float* db1 = (const float*)d_in[8];
    const float* dw2 = (const float*)d_in[9];
    const float* db2 = (const float*)d_in[10];
    const float* dw3 = (const float*)d_in[11];
    const float* db3 = (const float*)d_in[12];
    const int* idx   = (const int*)d_in[13];
    const float* mask= (const float*)d_in[14];
    float* out = (float*)d_out;
    u16* ws = (u16*)d_ws;

    const int B  = in_sizes[0] / SAMPLE;     // 8192
    const int G  = in_sizes[2];              // 510
    const int K  = in_sizes[1] / G;          // 28
    const int GK = in_sizes[1];

    pack_all<<<(NCHUNK + 255) / 256, 256, 0, stream>>>(w1, w2, dw1, dw2, dw3, ws);
    scatter_gw<<<(GK + 255) / 256, 256, 0, stream>>>(gw, mask, idx, ws, GK, K);
    ae_mfma<<<B / TB, NT, 0, stream>>>(x, gb, b1, b2, db1, db2, db3, ws, out);
}